// Round 6
// baseline (215.671 us; speedup 1.0000x reference)
//
#include <hip/hip_runtime.h>
#include <stdint.h>

#define BATCH 32
#define CIN   128
#define HH    56
#define WW    56
#define COUT  256
#define HP    58
#define WP    58

typedef __attribute__((ext_vector_type(8))) short short8;
typedef __attribute__((ext_vector_type(4))) float floatx4;

// async global->LDS, 16B per lane; LDS dest = wave-uniform base + lane*16
#define GLOAD_LDS16(gptr, lptr)                                          \
  __builtin_amdgcn_global_load_lds(                                      \
      (const __attribute__((address_space(1))) void*)(gptr),             \
      (__attribute__((address_space(3))) void*)(lptr), 16, 0, 0)

__device__ __forceinline__ unsigned short f32_to_bf16(float f) {
  unsigned int u = __float_as_uint(f);
  u = u + 0x7fffu + ((u >> 16) & 1u);
  return (unsigned short)(u >> 16);
}
__device__ __forceinline__ unsigned int pack2(float a, float b) {
  return (unsigned int)f32_to_bf16(a) | ((unsigned int)f32_to_bf16(b) << 16);
}

// ws layout: [xp_t: BATCH*HP*WP*CIN bf16][slack 1024][wt: 9*COUT*CIN bf16]
// xp_t NHWC padded: xp_t[((b*58+i)*58+j)*128+ci] = x[b][ci][i-1][j-1] or 0.
// With BM=224 (4h x 56w) conv A-reads stay within [0,WP) in both h and w:
// no overrun (SLACK retained but unused).

// Fused producers. Blocks [0,1856): pad+transpose one (b,i) row of xpt.
// Blocks [1856,2000): weight transpose (36864 uint4s, 144 blocks).
__global__ void producers_kernel(const float* __restrict__ x,
                                 const float* __restrict__ wsrc,
                                 unsigned short* __restrict__ xpt,
                                 unsigned short* __restrict__ wt) {
  const int t = threadIdx.x;
  if (blockIdx.x >= BATCH * HP) {  // weight transpose part
    const int o8 = (blockIdx.x - BATCH * HP) * 256 + t;
    const int r = o8 >> 12;
    const int rem = o8 & 4095;
    const int co = rem >> 4;
    const int ci0 = (rem & 15) * 8;
    const float* s = wsrc + ((size_t)co * CIN + ci0) * 9 + r;
    uint4 pk;
    pk.x = pack2(s[0 * 9], s[1 * 9]);
    pk.y = pack2(s[2 * 9], s[3 * 9]);
    pk.z = pack2(s[4 * 9], s[5 * 9]);
    pk.w = pack2(s[6 * 9], s[7 * 9]);
    *(uint4*)(wt + (size_t)o8 * 8) = pk;
    return;
  }

  const int blk = blockIdx.x;  // b*58 + i
  const int b = blk / HP;
  const int i = blk - b * HP;
  unsigned short* dst = xpt + (size_t)blk * (WP * CIN);

  if (i == 0 || i == HP - 1) {  // pure pad row: store zeros, no LDS
    const uint4 z = {0, 0, 0, 0};
    for (int idx = t; idx < 928; idx += 256)
      *(uint4*)(dst + (size_t)idx * 8) = z;
    return;
  }

  __shared__ float tile2[58 * 192];  // [w][octet(ci)*12 + ci&7]
  // zero pad cols w=0 and w=57 (128 ci each)
  {
    const int ci = t & 127;
    const int base = (t < 128) ? 0 : 57 * 192;
    tile2[base + (ci >> 3) * 12 + (ci & 7)] = 0.0f;
  }
  // load phase: ci = t>>1, seg = t&1 covers w = 1+seg*28 .. 1+seg*28+27
  {
    const int ci = t >> 1;
    const int seg = t & 1;
    const int cio = (ci >> 3) * 12 + (ci & 7);
    const float* row =
        x + (((size_t)b * CIN + ci) * HH + (i - 1)) * WW + seg * 28;
#pragma unroll
    for (int q = 0; q < 7; ++q) {
      const float4 v = *(const float4*)(row + q * 4);
      const int w0 = 1 + seg * 28 + q * 4;
      tile2[(w0 + 0) * 192 + cio] = v.x;
      tile2[(w0 + 1) * 192 + cio] = v.y;
      tile2[(w0 + 2) * 192 + cio] = v.z;
      tile2[(w0 + 3) * 192 + cio] = v.w;
    }
  }
  __syncthreads();
  // pack: idx -> j = idx>>4, octet o = idx&15; vector float4 reads
  for (int idx = t; idx < 928; idx += 256) {
    const int j = idx >> 4;
    const float* src = &tile2[j * 192 + (idx & 15) * 12];
    const float4 a = *(const float4*)(src);
    const float4 c = *(const float4*)(src + 4);
    uint4 pk;
    pk.x = pack2(a.x, a.y);
    pk.y = pack2(a.z, a.w);
    pk.z = pack2(c.x, c.y);
    pk.w = pack2(c.z, c.w);
    *(uint4*)(dst + (size_t)idx * 8) = pk;
  }
}

// 224x256 tile (BM=224 = 4h x 56w, zero M-padding), 8 waves (2M x 4N),
// 112x64 out/wave, 512 threads. K = 1152 as 36 stages of K=32 through a
// ring of 4 LDS slots (30 KB each), depth-3 prefetch via global_load_lds,
// counted s_waitcnt vmcnt(6) mid-loop, one s_barrier per stage, setprio
// around the MFMA cluster.
//
// ROUND-6 CHANGE — conflict-free-by-construction LDS layout: each 16x32
// subtile (16 rows x 32 k, 1 KB) is stored k-group-major so that chunk
// index within the subtile == lane id (chunk = laneKg*16 + laneM). A
// wave's frag ds_read_b128 is then addr = subtile_base + lane*16 —
// perfectly LINEAR, zero bank conflicts by definition, one addr VGPR +
// immediate offsets. The permutation lives entirely in the per-lane
// GLOBAL source address of global_load_lds (LDS dest stays linear, G21).
// A region: 14 subtiles (s = mm>>4) = 14336 B; B region: 16 subtiles
// (s = co>>4) = 16384 B; slot = 30720 B (same as round 5); per-wave
// gload counts identical to round 5 (waves 0-5: 4/stage, 6-7: 3/stage).
// Epilogue ni loop MUST stay unrolled (rule #20, round-3 post-mortem).
__global__ __launch_bounds__(512, 2) void conv_gemm_kernel(
    const unsigned short* __restrict__ xpt,
    const unsigned short* __restrict__ wt,
    const float* __restrict__ bias,
    float* __restrict__ out) {
  // slot = 15360 shorts: A at [0,7168), B at [7168,15360). 4 slots = 120 KB.
  __shared__ __align__(16) uint32_t smem[30720];
  short* const S = (short*)smem;
  float* const ep = (float*)smem;  // epilogue alias [64 co'][228]

  // bijective XCD chunking: 448 % 8 == 0, each XCD gets 56 contiguous mt
  const int g = blockIdx.x;
  const int mt = (g & 7) * 56 + (g >> 3);  // 0..447
  const int b = mt / 14;
  const int h0 = (mt - b * 14) * 4;

  const int t = threadIdx.x;
  const int lane = t & 63;
  const int wv = t >> 6;      // 0..7
  const int mw = wv >> 2;     // 0..1
  const int nw = wv & 3;      // 0..3
  const int laneM = lane & 15;
  const int laneKg = lane >> 4;     // 0..3 (k-chunk group)
  const int rowreg = laneKg * 4;
  const bool hasA2 = (wv < 6);  // wave-uniform: A chunks 512..895 (t<384)

  // A staging sources: chunk u -> subtile s = u>>6, w = u&63,
  // kg = w>>4, m = w&15, row mm = s*16+m (0..223 = hq*56+ww), k-off kg*8.
  const unsigned short* agA[2];
  {
    const int u0 = t;
    const int w0 = u0 & 63;
    const int mm0 = (u0 >> 6) * 16 + (w0 & 15);
    const int hq0 = mm0 / 56;
    const int ww0 = mm0 - hq0 * 56;
    agA[0] = xpt + ((size_t)((b * HP + h0 + hq0) * WP + ww0)) * CIN +
             (w0 >> 4) * 8;
    const int u1 = 512 + t;  // only t<384 issues this one
    const int w1 = u1 & 63;
    const int mm1 = (u1 >> 6) * 16 + (w1 & 15);
    const int hq1 = mm1 / 56;
    const int ww1 = mm1 - hq1 * 56;
    agA[1] = xpt + ((size_t)((b * HP + h0 + hq1) * WP + ww1)) * CIN +
             (w1 >> 4) * 8;
  }
  // B staging sources: chunk u -> co = (u>>6)*16 + (u&15), kg = (u>>4)&3
  const unsigned short* bg[2];
  bg[0] = wt + (size_t)((t >> 6) * 16 + (t & 15)) * CIN + ((t >> 4) & 3) * 8;
  bg[1] = wt + (size_t)(128 + (t >> 6) * 16 + (t & 15)) * CIN +
          ((t >> 4) & 3) * 8;

  const int dW = wv * 512;  // wave-uniform LDS dest offset (shorts)

  floatx4 acc[7][4] = {};

  // stage kk: tap r = kk>>2, ci-chunk = kk&3
  auto stageK = [&](int kk) {
    const int r = kk >> 2;
    const int dh = (r * 11) >> 5;  // r/3
    const int dw = r - dh * 3;
    const int aoff = (dh * WP + dw) * CIN + (kk & 3) * 32;
    const int boff = r * (COUT * CIN) + (kk & 3) * 32;
    short* const slot = S + (kk & 3) * 15360;
    GLOAD_LDS16(agA[0] + aoff, slot + dW);
    if (hasA2) GLOAD_LDS16(agA[1] + aoff, slot + 4096 + dW);
    GLOAD_LDS16(bg[0] + boff, slot + 7168 + dW);
    GLOAD_LDS16(bg[1] + boff, slot + 11264 + dW);
  };

  // prologue: stages 0..2 in flight; publish stage 0
  stageK(0);
  stageK(1);
  stageK(2);
  __builtin_amdgcn_sched_barrier(0);
  asm volatile("s_waitcnt vmcnt(6)" ::: "memory");
  __builtin_amdgcn_s_barrier();
  __builtin_amdgcn_sched_barrier(0);

  for (int kk = 0; kk < 36; ++kk) {
    const short* slot = S + (kk & 3) * 15360;
    short8 af[7], bf[4];
    // LINEAR frag reads: subtile base + lane*16B; zero bank conflicts.
#pragma unroll
    for (int mi = 0; mi < 7; ++mi)
      af[mi] = *(const short8*)&slot[(mw * 7 + mi) * 512 + lane * 8];
#pragma unroll
    for (int ni = 0; ni < 4; ++ni)
      bf[ni] = *(const short8*)&slot[7168 + (nw * 4 + ni) * 512 + lane * 8];
    if (kk <= 32) stageK(kk + 3);  // depth-3 prefetch into slot (kk+3)&3
    __builtin_amdgcn_sched_barrier(0);
    __builtin_amdgcn_s_setprio(1);
#pragma unroll
    for (int mi = 0; mi < 7; ++mi)
#pragma unroll
      for (int ni = 0; ni < 4; ++ni)
        acc[mi][ni] = __builtin_amdgcn_mfma_f32_16x16x32_bf16(
            af[mi], bf[ni], acc[mi][ni], 0, 0, 0);
    __builtin_amdgcn_s_setprio(0);
    // publish stage kk+1: leave deeper prefetches in flight (counted waits)
    if (kk <= 32)
      asm volatile("s_waitcnt vmcnt(6)" ::: "memory");
    else if (kk == 33)
      asm volatile("s_waitcnt vmcnt(3)" ::: "memory");
    else if (kk == 34)
      asm volatile("s_waitcnt vmcnt(0)" ::: "memory");
    if (kk < 35) {
      __builtin_amdgcn_s_barrier();
      __builtin_amdgcn_sched_barrier(0);
    }
  }

  // Epilogue: 4 chunks (ni) of 64 co' x 224 m via LDS -> dense 224B rows.
  // acc[mi][ni] lane l: m = mw*112+mi*16+(l>>4)*4+reg (= hq*56 + w),
  // co = nw*64+ni*16+(l&15). ni loop MUST be unrolled (rule #20).
#pragma unroll
  for (int ni = 0; ni < 4; ++ni) {
    __syncthreads();
#pragma unroll
    for (int mi = 0; mi < 7; ++mi)
      *(float4*)&ep[(nw * 16 + laneM) * 228 + mw * 112 + mi * 16 + rowreg] =
          *(float4*)&acc[mi][ni];
    __syncthreads();
#pragma unroll
    for (int rr = 0; rr < 32; ++rr) {
      const int rid = wv * 32 + rr;
      const int cp = rid >> 2;    // co' = (nw<<4)|laneM of producer
      const int hq2 = rid & 3;    // h offset within tile
      const int co = (cp >> 4) * 64 + ni * 16 + (cp & 15);
      const float bv = bias[co];
      if (lane < WW) {
        out[(((size_t)b * COUT + co) * HH + h0 + hq2) * WW + lane] =
            ep[cp * 228 + hq2 * 56 + lane] + bv;
      }
    }
  }
}

// Fallback if ws is too small: correct but slow.
__global__ void naive_conv_kernel(const float* __restrict__ x,
                                  const float* __restrict__ wgt,
                                  const float* __restrict__ bias,
                                  float* __restrict__ out, long n) {
  long idx = (long)blockIdx.x * 256 + threadIdx.x;
  if (idx >= n) return;
  int w = (int)(idx % WW);
  long q = idx / WW;
  int h = (int)(q % HH);
  q /= HH;
  int co = (int)(q % COUT);
  int b = (int)(q / COUT);
  float s = bias[co];
  for (int ci = 0; ci < CIN; ++ci) {
    const float* xp = x + (((size_t)b * CIN + ci) * HH) * WW;
    const float* wp = wgt + ((size_t)co * CIN + ci) * 9;
    for (int dh = 0; dh < 3; ++dh) {
      int hh = h + dh - 1;
      if (hh < 0 || hh >= HH) continue;
      for (int dw = 0; dw < 3; ++dw) {
        int ww2 = w + dw - 1;
        if (ww2 < 0 || ww2 >= WW) continue;
        s += xp[hh * WW + ww2] * wp[dh * 3 + dw];
      }
    }
  }
  out[idx] = s;
}

extern "C" void kernel_launch(void* const* d_in, const int* in_sizes, int n_in,
                              void* d_out, int out_size, void* d_ws,
                              size_t ws_size, hipStream_t stream) {
  const float* x = (const float*)d_in[0];
  const float* wgt = (const float*)d_in[1];
  const float* bias = (const float*)d_in[2];
  float* out = (float*)d_out;

  const size_t XPT = (size_t)BATCH * HP * WP * CIN;  // 13,778,944
  const size_t SLACK = 1024;
  const size_t WT = (size_t)9 * COUT * CIN;  // 294,912
  const size_t need = (XPT + SLACK + WT) * sizeof(unsigned short);

  if (ws_size >= need) {
    unsigned short* xpt = (unsigned short*)d_ws;
    unsigned short* wtp = xpt + XPT + SLACK;
    hipLaunchKernelGGL(producers_kernel, dim3(BATCH * HP + 144), dim3(256), 0,
                       stream, x, wgt, xpt, wtp);
    hipLaunchKernelGGL(conv_gemm_kernel, dim3(448), dim3(512), 0, stream,
                       xpt, wtp, bias, out);
  } else {
    long n = (long)out_size;
    hipLaunchKernelGGL(naive_conv_kernel, dim3((unsigned)((n + 255) / 256)),
                       dim3(256), 0, stream, x, wgt, bias, out, n);
  }
}

// Round 7
// 207.568 us; speedup vs baseline: 1.0390x; 1.0390x over previous
//
#include <hip/hip_runtime.h>
#include <stdint.h>

#define BATCH 32
#define CIN   128
#define HH    56
#define WW    56
#define COUT  256
#define HP    58
#define WP    58

typedef __attribute__((ext_vector_type(8))) short short8;
typedef __attribute__((ext_vector_type(4))) float floatx4;

// async global->LDS, 16B per lane; LDS dest = wave-uniform base + lane*16
#define GLOAD_LDS16(gptr, lptr)                                          \
  __builtin_amdgcn_global_load_lds(                                      \
      (const __attribute__((address_space(1))) void*)(gptr),             \
      (__attribute__((address_space(3))) void*)(lptr), 16, 0, 0)

__device__ __forceinline__ unsigned short f32_to_bf16(float f) {
  unsigned int u = __float_as_uint(f);
  u = u + 0x7fffu + ((u >> 16) & 1u);
  return (unsigned short)(u >> 16);
}
__device__ __forceinline__ unsigned int pack2(float a, float b) {
  return (unsigned int)f32_to_bf16(a) | ((unsigned int)f32_to_bf16(b) << 16);
}

// ws layout: [xp_t: BATCH*HP*WP*CIN bf16][slack 1024][wt: 9*COUT*CIN bf16]
// xp_t NHWC padded: xp_t[((b*58+i)*58+j)*128+ci] = x[b][ci][i-1][j-1] or 0.
// With BM=224 (4h x 56w) conv A-reads stay within [0,WP) in both h and w.

// Fused producers. Blocks [0,1856): pad+transpose one (b,i) row of xpt.
// Blocks [1856,2000): weight transpose (36864 uint4s, 144 blocks).
__global__ void producers_kernel(const float* __restrict__ x,
                                 const float* __restrict__ wsrc,
                                 unsigned short* __restrict__ xpt,
                                 unsigned short* __restrict__ wt) {
  const int t = threadIdx.x;
  if (blockIdx.x >= BATCH * HP) {  // weight transpose part
    const int o8 = (blockIdx.x - BATCH * HP) * 256 + t;
    const int r = o8 >> 12;
    const int rem = o8 & 4095;
    const int co = rem >> 4;
    const int ci0 = (rem & 15) * 8;
    const float* s = wsrc + ((size_t)co * CIN + ci0) * 9 + r;
    uint4 pk;
    pk.x = pack2(s[0 * 9], s[1 * 9]);
    pk.y = pack2(s[2 * 9], s[3 * 9]);
    pk.z = pack2(s[4 * 9], s[5 * 9]);
    pk.w = pack2(s[6 * 9], s[7 * 9]);
    *(uint4*)(wt + (size_t)o8 * 8) = pk;
    return;
  }

  const int blk = blockIdx.x;  // b*58 + i
  const int b = blk / HP;
  const int i = blk - b * HP;
  unsigned short* dst = xpt + (size_t)blk * (WP * CIN);

  if (i == 0 || i == HP - 1) {  // pure pad row: store zeros, no LDS
    const uint4 z = {0, 0, 0, 0};
    for (int idx = t; idx < 928; idx += 256)
      *(uint4*)(dst + (size_t)idx * 8) = z;
    return;
  }

  __shared__ float tile2[58 * 192];  // [w][octet(ci)*12 + ci&7]
  // zero pad cols w=0 and w=57 (128 ci each)
  {
    const int ci = t & 127;
    const int base = (t < 128) ? 0 : 57 * 192;
    tile2[base + (ci >> 3) * 12 + (ci & 7)] = 0.0f;
  }
  // load phase: ci = t>>1, seg = t&1 covers w = 1+seg*28 .. 1+seg*28+27
  {
    const int ci = t >> 1;
    const int seg = t & 1;
    const int cio = (ci >> 3) * 12 + (ci & 7);
    const float* row =
        x + (((size_t)b * CIN + ci) * HH + (i - 1)) * WW + seg * 28;
#pragma unroll
    for (int q = 0; q < 7; ++q) {
      const float4 v = *(const float4*)(row + q * 4);
      const int w0 = 1 + seg * 28 + q * 4;
      tile2[(w0 + 0) * 192 + cio] = v.x;
      tile2[(w0 + 1) * 192 + cio] = v.y;
      tile2[(w0 + 2) * 192 + cio] = v.z;
      tile2[(w0 + 3) * 192 + cio] = v.w;
    }
  }
  __syncthreads();
  // pack: idx -> j = idx>>4, octet o = idx&15; vector float4 reads
  for (int idx = t; idx < 928; idx += 256) {
    const int j = idx >> 4;
    const float* src = &tile2[j * 192 + (idx & 15) * 12];
    const float4 a = *(const float4*)(src);
    const float4 c = *(const float4*)(src + 4);
    uint4 pk;
    pk.x = pack2(a.x, a.y);
    pk.y = pack2(a.z, a.w);
    pk.z = pack2(c.x, c.y);
    pk.w = pack2(c.z, c.w);
    *(uint4*)(dst + (size_t)idx * 8) = pk;
  }
}

// 224x256 tile (BM=224 = 4h x 56w, zero M-padding), 8 waves (2M x 4N),
// 112x64 out/wave, 512 threads. K = 1152 as 36 sub-stages of K=32 through
// a ring of 4 LDS sub-slots (15 KB each), processed in PAIRS: one
// prefetch burst + 56 MFMAs + ONE vmcnt(0)+s_barrier per pair (18 barrier
// round-trips instead of 36 — round-7 change; barrier-coupled latency was
// the unexplained 2.4x over the work terms). Sub-slot layout, staging
// addresses and frag reads are byte-identical to round 5 (best measured:
// 87.7 us; round-6 proved the 4-per-b128 conflict counter is FREE and the
// linear-LDS variant's scattered global staging cost 8 us -> reverted).
// Ring safety: pair p reads sub-slots (2p)&3,(2p+1)&3 and writes
// (2p+2)&3,(2p+3)&3 — disjoint mod 4. Prefetch issues at pair start;
// vmcnt(0) drains own loads ~one full pair (~2x compute) after issue.
// Epilogue ni loop MUST stay unrolled (rule #20, round-3 post-mortem).
__global__ __launch_bounds__(512, 2) void conv_gemm_kernel(
    const unsigned short* __restrict__ xpt,
    const unsigned short* __restrict__ wt,
    const float* __restrict__ bias,
    float* __restrict__ out) {
  // sub-slot = 15360 shorts: A at [0,7168), B at [7168,15360). 4 = 120 KB.
  __shared__ __align__(16) uint32_t smem[30720];
  short* const S = (short*)smem;
  float* const ep = (float*)smem;  // epilogue alias [64 co'][228]

  // bijective XCD chunking: 448 % 8 == 0, each XCD gets 56 contiguous mt
  const int g = blockIdx.x;
  const int mt = (g & 7) * 56 + (g >> 3);  // 0..447
  const int b = mt / 14;
  const int h0 = (mt - b * 14) * 4;

  const int t = threadIdx.x;
  const int lane = t & 63;
  const int wv = t >> 6;      // 0..7
  const int mw = wv >> 2;     // 0..1
  const int nw = wv & 3;      // 0..3
  const int laneM = lane & 15;
  const int laneKg = lane >> 4;     // 0..3 (k-chunk group)
  const int rowreg = laneKg * 4;
  const bool hasA2 = (wv < 6);  // wave-uniform: A chunks 512..895

  // A staging: chunk u -> row mm = u>>2 (0..223 = hq*56+w), k-chunk p = u&3
  const unsigned short* agA[2];
  {
    const int mm1 = t >> 2;
    const int hq1 = mm1 / 56;
    const int w1 = mm1 - hq1 * 56;
    agA[0] = xpt + ((size_t)((b * HP + h0 + hq1) * WP + w1)) * CIN +
             (t & 3) * 8;
    const int mm2 = 128 + (t >> 2);
    const int hq2 = mm2 / 56;
    const int w2 = mm2 - hq2 * 56;
    agA[1] = xpt + ((size_t)((b * HP + h0 + hq2) * WP + w2)) * CIN +
             (t & 3) * 8;
  }
  // B staging: chunk u -> co = u>>2, p = u&3
  const unsigned short* bg[2];
  bg[0] = wt + (size_t)(t >> 2) * CIN + (t & 3) * 8;
  bg[1] = wt + (size_t)(128 + (t >> 2)) * CIN + (t & 3) * 8;

  const int dW = wv * 512;  // wave-uniform LDS dest offset (shorts)

  floatx4 acc[7][4] = {};

  // sub-stage kk: tap r = kk>>2, ci-chunk = kk&3
  auto stageK = [&](int kk) {
    const int r = kk >> 2;
    const int dh = (r * 11) >> 5;  // r/3
    const int dw = r - dh * 3;
    const int aoff = (dh * WP + dw) * CIN + (kk & 3) * 32;
    const int boff = r * (COUT * CIN) + (kk & 3) * 32;
    short* const slot = S + (kk & 3) * 15360;
    GLOAD_LDS16(agA[0] + aoff, slot + dW);
    if (hasA2) GLOAD_LDS16(agA[1] + aoff, slot + 4096 + dW);
    GLOAD_LDS16(bg[0] + boff, slot + 7168 + dW);
    GLOAD_LDS16(bg[1] + boff, slot + 11264 + dW);
  };

  // prologue: pair 0 (sub-stages 0,1) staged and published
  stageK(0);
  stageK(1);
  __builtin_amdgcn_sched_barrier(0);
  asm volatile("s_waitcnt vmcnt(0)" ::: "memory");
  __builtin_amdgcn_s_barrier();
  __builtin_amdgcn_sched_barrier(0);

  for (int p = 0; p < 18; ++p) {
    const int kk0 = 2 * p;
    // prefetch next pair's sub-slots (disjoint from this pair's, mod 4)
    if (p < 17) {
      stageK(kk0 + 2);
      stageK(kk0 + 3);
    }
    __builtin_amdgcn_sched_barrier(0);
#pragma unroll
    for (int s = 0; s < 2; ++s) {
      const int kk = kk0 + s;
      const short* slot = S + (kk & 3) * 15360;
      short8 af[7], bf[4];
#pragma unroll
      for (int mi = 0; mi < 7; ++mi)
        af[mi] = *(const short8*)&slot[(mw * 112 + mi * 16 + laneM) * 32 +
                                       laneKg * 8];
#pragma unroll
      for (int ni = 0; ni < 4; ++ni)
        bf[ni] = *(const short8*)&slot[7168 +
                                       (nw * 64 + ni * 16 + laneM) * 32 +
                                       laneKg * 8];
      __builtin_amdgcn_s_setprio(1);
#pragma unroll
      for (int mi = 0; mi < 7; ++mi)
#pragma unroll
        for (int ni = 0; ni < 4; ++ni)
          acc[mi][ni] = __builtin_amdgcn_mfma_f32_16x16x32_bf16(
              af[mi], bf[ni], acc[mi][ni], 0, 0, 0);
      __builtin_amdgcn_s_setprio(0);
    }
    // one drain + one barrier per pair: own prefetch loads were issued a
    // full pair (~2x compute) ago -> drain is cheap
    asm volatile("s_waitcnt vmcnt(0)" ::: "memory");
    if (p < 17) {
      __builtin_amdgcn_s_barrier();
      __builtin_amdgcn_sched_barrier(0);
    }
  }

  // Epilogue: 4 chunks (ni) of 64 co' x 224 m via LDS -> dense 224B rows.
  // acc[mi][ni] lane l: m = mw*112+mi*16+(l>>4)*4+reg (= hq*56 + w),
  // co = nw*64+ni*16+(l&15). ni loop MUST be unrolled (rule #20).
#pragma unroll
  for (int ni = 0; ni < 4; ++ni) {
    __syncthreads();
#pragma unroll
    for (int mi = 0; mi < 7; ++mi)
      *(float4*)&ep[(nw * 16 + laneM) * 228 + mw * 112 + mi * 16 + rowreg] =
          *(float4*)&acc[mi][ni];
    __syncthreads();
#pragma unroll
    for (int rr = 0; rr < 32; ++rr) {
      const int rid = wv * 32 + rr;
      const int cp = rid >> 2;    // co' = (nw<<4)|laneM of producer
      const int hq2 = rid & 3;    // h offset within tile
      const int co = (cp >> 4) * 64 + ni * 16 + (cp & 15);
      const float bv = bias[co];
      if (lane < WW) {
        out[(((size_t)b * COUT + co) * HH + h0 + hq2) * WW + lane] =
            ep[cp * 228 + hq2 * 56 + lane] + bv;
      }
    }
  }
}

// Fallback if ws is too small: correct but slow.
__global__ void naive_conv_kernel(const float* __restrict__ x,
                                  const float* __restrict__ wgt,
                                  const float* __restrict__ bias,
                                  float* __restrict__ out, long n) {
  long idx = (long)blockIdx.x * 256 + threadIdx.x;
  if (idx >= n) return;
  int w = (int)(idx % WW);
  long q = idx / WW;
  int h = (int)(q % HH);
  q /= HH;
  int co = (int)(q % COUT);
  int b = (int)(q / COUT);
  float s = bias[co];
  for (int ci = 0; ci < CIN; ++ci) {
    const float* xp = x + (((size_t)b * CIN + ci) * HH) * WW;
    const float* wp = wgt + ((size_t)co * CIN + ci) * 9;
    for (int dh = 0; dh < 3; ++dh) {
      int hh = h + dh - 1;
      if (hh < 0 || hh >= HH) continue;
      for (int dw = 0; dw < 3; ++dw) {
        int ww2 = w + dw - 1;
        if (ww2 < 0 || ww2 >= WW) continue;
        s += xp[hh * WW + ww2] * wp[dh * 3 + dw];
      }
    }
  }
  out[idx] = s;
}

extern "C" void kernel_launch(void* const* d_in, const int* in_sizes, int n_in,
                              void* d_out, int out_size, void* d_ws,
                              size_t ws_size, hipStream_t stream) {
  const float* x = (const float*)d_in[0];
  const float* wgt = (const float*)d_in[1];
  const float* bias = (const float*)d_in[2];
  float* out = (float*)d_out;

  const size_t XPT = (size_t)BATCH * HP * WP * CIN;  // 13,778,944
  const size_t SLACK = 1024;
  const size_t WT = (size_t)9 * COUT * CIN;  // 294,912
  const size_t need = (XPT + SLACK + WT) * sizeof(unsigned short);

  if (ws_size >= need) {
    unsigned short* xpt = (unsigned short*)d_ws;
    unsigned short* wtp = xpt + XPT + SLACK;
    hipLaunchKernelGGL(producers_kernel, dim3(BATCH * HP + 144), dim3(256), 0,
                       stream, x, wgt, xpt, wtp);
    hipLaunchKernelGGL(conv_gemm_kernel, dim3(448), dim3(512), 0, stream,
                       xpt, wtp, bias, out);
  } else {
    long n = (long)out_size;
    hipLaunchKernelGGL(naive_conv_kernel, dim3((unsigned)((n + 255) / 256)),
                       dim3(256), 0, stream, x, wgt, bias, out, n);
  }
}